// Round 2
// baseline (68.798 us; speedup 1.0000x reference)
//
#include <hip/hip_runtime.h>

#define REF_EPS 0.001f

// Kernel 1: per flattened position k, compute 4 corner indices + 4 coeffs for
// each n, with coeffs pre-multiplied by the all-N validity mask.
// grid layout: (N, H, W, 2) float32 -> float2 at index n*HW + k.
__global__ __launch_bounds__(256)
void precompute_kernel(const float* __restrict__ grid,
                       int4* __restrict__ corners_out,
                       float4* __restrict__ coeffs_out,
                       int N, int H, int W) {
    const int HW = H * W;
    const int k = blockIdx.x * 256 + threadIdx.x;
    if (k >= HW) return;

    const float2* gp = (const float2*)grid;
    const float hx = (float)(H - 1);
    const float wy = (float)(W - 1);

    int4   crn[8];
    float4 cf[8];
    bool valid = true;
    const int Nn = (N < 8) ? N : 8;

    for (int n = 0; n < Nn; ++n) {
        float2 g = gp[(size_t)n * HW + k];
        float g0 = g.x;
        float g1 = g.y;

        valid = valid && (g0 >= -REF_EPS) && (g0 <= hx + REF_EPS)
                      && (g1 >= -REF_EPS) && (g1 <= wy + REF_EPS);

        float gx = fminf(fmaxf(g0, REF_EPS), hx - REF_EPS);
        float gy = fminf(fmaxf(g1, REF_EPS), wy - REF_EPS);
        float ixf = floorf(gx);
        float iyf = floorf(gy);
        float fx = gx - ixf;
        float fy = gy - iyf;
        int ix = (int)ixf;
        int iy = (int)iyf;
        int c0 = ix * W + iy;
        // offsets (0,0),(0,1),(1,0),(1,1) -> c0, c0+1, c0+W, c0+W+1
        crn[n] = make_int4(c0, c0 + 1, c0 + W, c0 + W + 1);
        float omfx = 1.0f - fx;
        // coeffs = outer([1-fx, fx], [fx, fy]) flattened (faithful to source)
        cf[n] = make_float4(omfx * fx, omfx * fy, fx * fx, fx * fy);
    }

    const float vm = valid ? 1.0f : 0.0f;
    for (int n = 0; n < Nn; ++n) {
        size_t idx = (size_t)n * HW + k;
        corners_out[idx] = crn[n];
        float4 c = cf[n];
        coeffs_out[idx] = make_float4(c.x * vm, c.y * vm, c.z * vm, c.w * vm);
    }
}

// Kernel 2: one block per (n,c) row. Stage the x row (HW floats, 16 KB) into
// LDS, then gather 4 corners per output position. Random gathers hit LDS,
// corner/coeff reads are coalesced int4/float4, stores are coalesced float.
__global__ __launch_bounds__(256)
void apply_kernel(const float* __restrict__ x,
                  const int4* __restrict__ corners,
                  const float4* __restrict__ coeffs,
                  float* __restrict__ out,
                  int C, int HW) {
    extern __shared__ float xs[];  // HW floats

    const int row = blockIdx.x;        // n*C + c
    const int n = row / C;
    const int tid = threadIdx.x;

    const float* xrow = x + (size_t)row * HW;

    // vectorized stage: 4 floats per float4
    const float4* xv = (const float4*)xrow;
    const int nvec = HW >> 2;
    for (int i = tid; i < nvec; i += 256) {
        float4 v = xv[i];
        int b = i << 2;
        xs[b + 0] = v.x;
        xs[b + 1] = v.y;
        xs[b + 2] = v.z;
        xs[b + 3] = v.w;
    }
    for (int i = (nvec << 2) + tid; i < HW; i += 256) {  // tail (HW % 4 != 0)
        xs[i] = xrow[i];
    }
    __syncthreads();

    const int4*   crow = corners + (size_t)n * HW;
    const float4* wrow = coeffs + (size_t)n * HW;
    float* orow = out + (size_t)row * HW;

    for (int k = tid; k < HW; k += 256) {
        int4 cr = crow[k];
        float4 w = wrow[k];
        float r = xs[cr.x] * w.x + xs[cr.y] * w.y
                + xs[cr.z] * w.z + xs[cr.w] * w.w;
        orow[k] = r;
    }
}

extern "C" void kernel_launch(void* const* d_in, const int* in_sizes, int n_in,
                              void* d_out, int out_size, void* d_ws, size_t ws_size,
                              hipStream_t stream) {
    const float* x    = (const float*)d_in[0];  // (N, C, HW) fp32
    const float* grid = (const float*)d_in[1];  // (N, H, W, 2) fp32
    float* out = (float*)d_out;                 // (N, C, HW) fp32

    const int H = 64, W = 64;
    const int HW = H * W;
    const int N = in_sizes[1] / (HW * 2);
    const int C = in_sizes[0] / (N * HW);

    int4*   corners = (int4*)d_ws;
    float4* coeffs  = (float4*)((char*)d_ws + (size_t)N * HW * sizeof(int4));

    const int blocksA = (HW + 255) / 256;
    hipLaunchKernelGGL(precompute_kernel, dim3(blocksA), dim3(256), 0, stream,
                       grid, corners, coeffs, N, H, W);

    const size_t shmem = (size_t)HW * sizeof(float);  // 16 KB for 64x64
    hipLaunchKernelGGL(apply_kernel, dim3(N * C), dim3(256), shmem, stream,
                       x, corners, coeffs, out, C, HW);
}

// Round 3
// 65.932 us; speedup vs baseline: 1.0435x; 1.0435x over previous
//
#include <hip/hip_runtime.h>

#define REF_EPS 0.001f

// One block per (n,c) row of x/out. The block:
//   1. stages its 16 KB x row into LDS (coalesced float4),
//   2. each thread recomputes corners/coeffs for its 4 consecutive k's
//      straight from grid (128 KB total, L2-resident -> cheap redundant
//      recompute beats a serialized low-occupancy pre-pass: R2 post-mortem),
//   3. gathers 4 LDS values per k, fma, float4 store.
// 1024 threads/block -> 512 blocks x 16 waves = 32 waves/CU (max occupancy).
__global__ __launch_bounds__(1024)
void fused_remap_kernel(const float* __restrict__ x,
                        const float* __restrict__ grid,
                        float* __restrict__ out,
                        int N, int C, int H, int W) {
    const int HW = H * W;
    extern __shared__ float xs[];  // HW floats (16 KB for 64x64)

    const int row = blockIdx.x;    // n*C + c
    const int n = row / C;
    const int tid = threadIdx.x;

    // ---- stage x row into LDS, vectorized ----
    const float4* xv = (const float4*)(x + (size_t)row * HW);
    float4* xsv = (float4*)xs;
    const int nvec = HW >> 2;
    for (int i = tid; i < nvec; i += 1024) {
        xsv[i] = xv[i];
    }
    __syncthreads();

    const float hx = (float)(H - 1);
    const float wy = (float)(W - 1);
    const float4* g4 = (const float4*)grid;        // 2 (x,y) pairs per float4
    float4* ov = (float4*)(out + (size_t)row * HW);

    for (int k0 = tid << 2; k0 < HW; k0 += 1024 << 2) {
        // ---- validity across ALL n, own-n grid values, for k0..k0+3 ----
        bool valid[4] = {true, true, true, true};
        float g0n[4], g1n[4];
        for (int m = 0; m < N; ++m) {
            size_t base = ((size_t)m * HW + k0) >> 1;  // k0 even
            float4 a = g4[base];      // (gx[k0],   gy[k0],   gx[k0+1], gy[k0+1])
            float4 b = g4[base + 1];  // (gx[k0+2], gy[k0+2], gx[k0+3], gy[k0+3])
            valid[0] = valid[0] && (a.x >= -REF_EPS) && (a.x <= hx + REF_EPS)
                                && (a.y >= -REF_EPS) && (a.y <= wy + REF_EPS);
            valid[1] = valid[1] && (a.z >= -REF_EPS) && (a.z <= hx + REF_EPS)
                                && (a.w >= -REF_EPS) && (a.w <= wy + REF_EPS);
            valid[2] = valid[2] && (b.x >= -REF_EPS) && (b.x <= hx + REF_EPS)
                                && (b.y >= -REF_EPS) && (b.y <= wy + REF_EPS);
            valid[3] = valid[3] && (b.z >= -REF_EPS) && (b.z <= hx + REF_EPS)
                                && (b.w >= -REF_EPS) && (b.w <= wy + REF_EPS);
            if (m == n) {
                g0n[0] = a.x; g1n[0] = a.y;
                g0n[1] = a.z; g1n[1] = a.w;
                g0n[2] = b.x; g1n[2] = b.y;
                g0n[3] = b.z; g1n[3] = b.w;
            }
        }

        // ---- per-k: clip/floor/frac -> corners + coeffs -> LDS gather ----
        float4 res;
        float* resp = &res.x;
        #pragma unroll
        for (int j = 0; j < 4; ++j) {
            float gx = fminf(fmaxf(g0n[j], REF_EPS), hx - REF_EPS);
            float gy = fminf(fmaxf(g1n[j], REF_EPS), wy - REF_EPS);
            float ixf = floorf(gx);
            float iyf = floorf(gy);
            float fx = gx - ixf;
            float fy = gy - iyf;
            int c0 = (int)ixf * W + (int)iyf;
            float omfx = 1.0f - fx;
            // coeffs = outer([1-fx, fx], [fx, fy]) flattened (faithful to source)
            float r = xs[c0]         * (omfx * fx)
                    + xs[c0 + 1]     * (omfx * fy)
                    + xs[c0 + W]     * (fx * fx)
                    + xs[c0 + W + 1] * (fx * fy);
            resp[j] = valid[j] ? r : 0.0f;
        }
        ov[k0 >> 2] = res;
    }
}

extern "C" void kernel_launch(void* const* d_in, const int* in_sizes, int n_in,
                              void* d_out, int out_size, void* d_ws, size_t ws_size,
                              hipStream_t stream) {
    const float* x    = (const float*)d_in[0];  // (N, C, HW) fp32
    const float* grid = (const float*)d_in[1];  // (N, H, W, 2) fp32
    float* out = (float*)d_out;                 // (N, C, HW) fp32

    const int H = 64, W = 64;
    const int HW = H * W;
    const int N = in_sizes[1] / (HW * 2);
    const int C = in_sizes[0] / (N * HW);

    const size_t shmem = (size_t)HW * sizeof(float);  // 16 KB
    hipLaunchKernelGGL(fused_remap_kernel, dim3(N * C), dim3(1024), shmem, stream,
                       x, grid, out, N, C, H, W);
}

// Round 4
// 64.366 us; speedup vs baseline: 1.0688x; 1.0243x over previous
//
#include <hip/hip_runtime.h>

#define REF_EPS 0.001f

// ---------------- specialized fused kernel (compile-time shapes) ------------
// One block per (n,c) row. Stage 16 KB x row -> LDS, recompute validity (all
// N grids, fully unrolled so all 8 dwordx4 loads are in flight together) and
// bilinear coeffs from grid (128 KB, L2-hot), gather 4 corners per k from
// LDS, float4 store. 1024 threads x 4 k's = HW exactly.
template<int N, int C, int H, int W>
__global__ __launch_bounds__(1024)
void fused_remap_t(const float* __restrict__ x,
                   const float* __restrict__ grid,
                   float* __restrict__ out) {
    constexpr int HW = H * W;
    __shared__ float xs[HW];

    const int row = blockIdx.x;      // n*C + c
    const int n = row / C;           // constexpr C -> shift
    const int tid = threadIdx.x;

    // ---- stage x row into LDS: exactly one float4 per thread ----
    const float4* xv = (const float4*)(x + (size_t)row * HW);
    ((float4*)xs)[tid] = xv[tid];
    __syncthreads();

    constexpr float hx = (float)(H - 1);
    constexpr float wy = (float)(W - 1);
    const float4* g4 = (const float4*)grid;   // 2 (gx,gy) pairs per float4
    const int k0 = tid << 2;                  // 4 consecutive k's per thread

    // ---- validity across ALL n (unrolled: 8 loads issued together) ----
    bool v[4] = {true, true, true, true};
    #pragma unroll
    for (int m = 0; m < N; ++m) {
        const int base = (m * HW + k0) >> 1;
        float4 a = g4[base];       // gx[k0],gy[k0],gx[k0+1],gy[k0+1]
        float4 b = g4[base + 1];   // gx[k0+2],gy[k0+2],gx[k0+3],gy[k0+3]
        v[0] = v[0] && (a.x >= -REF_EPS) && (a.x <= hx + REF_EPS)
                    && (a.y >= -REF_EPS) && (a.y <= wy + REF_EPS);
        v[1] = v[1] && (a.z >= -REF_EPS) && (a.z <= hx + REF_EPS)
                    && (a.w >= -REF_EPS) && (a.w <= wy + REF_EPS);
        v[2] = v[2] && (b.x >= -REF_EPS) && (b.x <= hx + REF_EPS)
                    && (b.y >= -REF_EPS) && (b.y <= wy + REF_EPS);
        v[3] = v[3] && (b.z >= -REF_EPS) && (b.z <= hx + REF_EPS)
                    && (b.w >= -REF_EPS) && (b.w <= wy + REF_EPS);
    }

    // ---- own-n grid values (L2-hot re-read; keeps validity loop lean) ----
    const int nb = (n * HW + k0) >> 1;
    float4 ga = g4[nb];
    float4 gb = g4[nb + 1];
    float g0[4] = {ga.x, ga.z, gb.x, gb.z};
    float g1[4] = {ga.y, ga.w, gb.y, gb.w};

    float4 res;
    float* resp = &res.x;
    #pragma unroll
    for (int j = 0; j < 4; ++j) {
        float gx = fminf(fmaxf(g0[j], REF_EPS), hx - REF_EPS);
        float gy = fminf(fmaxf(g1[j], REF_EPS), wy - REF_EPS);
        float ixf = floorf(gx);
        float iyf = floorf(gy);
        float fx = gx - ixf;
        float fy = gy - iyf;
        int c0 = (int)ixf * W + (int)iyf;
        float omfx = 1.0f - fx;
        // coeffs = outer([1-fx, fx], [fx, fy]) flattened (faithful to source)
        float r = xs[c0]         * (omfx * fx)
                + xs[c0 + 1]     * (omfx * fy)
                + xs[c0 + W]     * (fx * fx)
                + xs[c0 + W + 1] * (fx * fy);
        resp[j] = v[j] ? r : 0.0f;   // select, not multiply: kills NaN garbage
    }
    ((float4*)(out + (size_t)row * HW))[tid] = res;
}

// ---------------- generic fallback (runtime shapes) -------------------------
__global__ __launch_bounds__(1024)
void fused_remap_generic(const float* __restrict__ x,
                         const float* __restrict__ grid,
                         float* __restrict__ out,
                         int N, int C, int H, int W) {
    const int HW = H * W;
    extern __shared__ float xs[];
    const int row = blockIdx.x;
    const int n = row / C;
    const int tid = threadIdx.x;

    for (int i = tid; i < HW; i += 1024) xs[i] = x[(size_t)row * HW + i];
    __syncthreads();

    const float hx = (float)(H - 1);
    const float wy = (float)(W - 1);

    for (int k = tid; k < HW; k += 1024) {
        bool valid = true;
        for (int m = 0; m < N; ++m) {
            float a = grid[((size_t)m * HW + k) * 2 + 0];
            float b = grid[((size_t)m * HW + k) * 2 + 1];
            valid = valid && (a >= -REF_EPS) && (a <= hx + REF_EPS)
                          && (b >= -REF_EPS) && (b <= wy + REF_EPS);
        }
        float g0v = grid[((size_t)n * HW + k) * 2 + 0];
        float g1v = grid[((size_t)n * HW + k) * 2 + 1];
        float gx = fminf(fmaxf(g0v, REF_EPS), hx - REF_EPS);
        float gy = fminf(fmaxf(g1v, REF_EPS), wy - REF_EPS);
        float ixf = floorf(gx), iyf = floorf(gy);
        float fx = gx - ixf, fy = gy - iyf;
        int c0 = (int)ixf * W + (int)iyf;
        float omfx = 1.0f - fx;
        float r = xs[c0] * (omfx * fx) + xs[c0 + 1] * (omfx * fy)
                + xs[c0 + W] * (fx * fx) + xs[c0 + W + 1] * (fx * fy);
        out[(size_t)row * HW + k] = valid ? r : 0.0f;
    }
}

extern "C" void kernel_launch(void* const* d_in, const int* in_sizes, int n_in,
                              void* d_out, int out_size, void* d_ws, size_t ws_size,
                              hipStream_t stream) {
    const float* x    = (const float*)d_in[0];  // (N, C, HW) fp32
    const float* grid = (const float*)d_in[1];  // (N, H, W, 2) fp32
    float* out = (float*)d_out;                 // (N, C, HW) fp32

    const int H = 64, W = 64;
    const int HW = H * W;
    const int N = in_sizes[1] / (HW * 2);
    const int C = in_sizes[0] / (N * HW);

    if (N == 4 && C == 128) {
        hipLaunchKernelGGL((fused_remap_t<4, 128, 64, 64>), dim3(N * C),
                           dim3(1024), 0, stream, x, grid, out);
    } else {
        const size_t shmem = (size_t)HW * sizeof(float);
        hipLaunchKernelGGL(fused_remap_generic, dim3(N * C), dim3(1024), shmem,
                           stream, x, grid, out, N, C, H, W);
    }
}

// Round 5
// 63.051 us; speedup vs baseline: 1.0911x; 1.0209x over previous
//
#include <hip/hip_runtime.h>

#define REF_EPS 0.001f

// Specialized fused kernel, 2 c-rows per block (rows contiguous in memory):
// grid-validity + bilinear coeffs computed ONCE per (n,k) pair of rows,
// amortizing the redundant grid recompute (R4 post-mortem: ~half the
// attackable kernel time was per-row grid L2 traffic + coeff VALU).
// 256 blocks x 1024 threads, 32 KB LDS -> 16 waves on every CU.
template<int N, int C, int H, int W>
__global__ __launch_bounds__(1024)
void fused_remap2_t(const float* __restrict__ x,
                    const float* __restrict__ grid,
                    float* __restrict__ out) {
    constexpr int HW = H * W;
    constexpr int CB = C / 2;          // row-pairs per n
    __shared__ float xs0[HW];
    __shared__ float xs1[HW];

    const int n = blockIdx.x / CB;     // constexpr -> shift
    const int tid = threadIdx.x;
    const size_t row0 = (size_t)blockIdx.x * 2;   // = n*C + 2*cb

    // ---- stage two x rows into LDS: one float4 per thread per row ----
    const float4* xv = (const float4*)(x + row0 * HW);
    ((float4*)xs0)[tid] = xv[tid];
    ((float4*)xs1)[tid] = xv[tid + (HW >> 2)];
    __syncthreads();

    constexpr float hx = (float)(H - 1);
    constexpr float wy = (float)(W - 1);
    const float4* g4 = (const float4*)grid;   // 2 (gx,gy) pairs per float4
    const int k0 = tid << 2;                  // 4 consecutive k's per thread

    // ---- validity across ALL n (unrolled: 8 loads in flight together) ----
    bool v[4] = {true, true, true, true};
    #pragma unroll
    for (int m = 0; m < N; ++m) {
        const int base = (m * HW + k0) >> 1;
        float4 a = g4[base];       // gx[k0],gy[k0],gx[k0+1],gy[k0+1]
        float4 b = g4[base + 1];   // gx[k0+2],gy[k0+2],gx[k0+3],gy[k0+3]
        v[0] = v[0] && (a.x >= -REF_EPS) && (a.x <= hx + REF_EPS)
                    && (a.y >= -REF_EPS) && (a.y <= wy + REF_EPS);
        v[1] = v[1] && (a.z >= -REF_EPS) && (a.z <= hx + REF_EPS)
                    && (a.w >= -REF_EPS) && (a.w <= wy + REF_EPS);
        v[2] = v[2] && (b.x >= -REF_EPS) && (b.x <= hx + REF_EPS)
                    && (b.y >= -REF_EPS) && (b.y <= wy + REF_EPS);
        v[3] = v[3] && (b.z >= -REF_EPS) && (b.z <= hx + REF_EPS)
                    && (b.w >= -REF_EPS) && (b.w <= wy + REF_EPS);
    }

    // ---- own-n grid values (L2-hot re-read) ----
    const int nb = (n * HW + k0) >> 1;
    float4 ga = g4[nb];
    float4 gb = g4[nb + 1];
    float g0[4] = {ga.x, ga.z, gb.x, gb.z};
    float g1[4] = {ga.y, ga.w, gb.y, gb.w};

    float4 r0, r1;
    float* r0p = &r0.x;
    float* r1p = &r1.x;
    #pragma unroll
    for (int j = 0; j < 4; ++j) {
        float gx = fminf(fmaxf(g0[j], REF_EPS), hx - REF_EPS);
        float gy = fminf(fmaxf(g1[j], REF_EPS), wy - REF_EPS);
        float ixf = floorf(gx);
        float iyf = floorf(gy);
        float fx = gx - ixf;
        float fy = gy - iyf;
        int c0 = (int)ixf * W + (int)iyf;
        float omfx = 1.0f - fx;
        // coeffs = outer([1-fx, fx], [fx, fy]) flattened (faithful to source)
        float w0 = omfx * fx, w1 = omfx * fy, w2 = fx * fx, w3 = fx * fy;
        // adjacent pairs (c0,c0+1) / (c0+W,c0+W+1) -> compiler emits ds_read2_b32
        float a0 = xs0[c0] * w0 + xs0[c0 + 1] * w1
                 + xs0[c0 + W] * w2 + xs0[c0 + W + 1] * w3;
        float a1 = xs1[c0] * w0 + xs1[c0 + 1] * w1
                 + xs1[c0 + W] * w2 + xs1[c0 + W + 1] * w3;
        r0p[j] = v[j] ? a0 : 0.0f;   // select, not multiply: kills NaN garbage
        r1p[j] = v[j] ? a1 : 0.0f;
    }
    float4* ov = (float4*)(out + row0 * HW);
    ov[tid] = r0;
    ov[tid + (HW >> 2)] = r1;
}

// ---------------- generic fallback (runtime shapes) -------------------------
__global__ __launch_bounds__(1024)
void fused_remap_generic(const float* __restrict__ x,
                         const float* __restrict__ grid,
                         float* __restrict__ out,
                         int N, int C, int H, int W) {
    const int HW = H * W;
    extern __shared__ float xs[];
    const int row = blockIdx.x;
    const int n = row / C;
    const int tid = threadIdx.x;

    for (int i = tid; i < HW; i += 1024) xs[i] = x[(size_t)row * HW + i];
    __syncthreads();

    const float hx = (float)(H - 1);
    const float wy = (float)(W - 1);

    for (int k = tid; k < HW; k += 1024) {
        bool valid = true;
        for (int m = 0; m < N; ++m) {
            float a = grid[((size_t)m * HW + k) * 2 + 0];
            float b = grid[((size_t)m * HW + k) * 2 + 1];
            valid = valid && (a >= -REF_EPS) && (a <= hx + REF_EPS)
                          && (b >= -REF_EPS) && (b <= wy + REF_EPS);
        }
        float g0v = grid[((size_t)n * HW + k) * 2 + 0];
        float g1v = grid[((size_t)n * HW + k) * 2 + 1];
        float gx = fminf(fmaxf(g0v, REF_EPS), hx - REF_EPS);
        float gy = fminf(fmaxf(g1v, REF_EPS), wy - REF_EPS);
        float ixf = floorf(gx), iyf = floorf(gy);
        float fx = gx - ixf, fy = gy - iyf;
        int c0 = (int)ixf * W + (int)iyf;
        float omfx = 1.0f - fx;
        float r = xs[c0] * (omfx * fx) + xs[c0 + 1] * (omfx * fy)
                + xs[c0 + W] * (fx * fx) + xs[c0 + W + 1] * (fx * fy);
        out[(size_t)row * HW + k] = valid ? r : 0.0f;
    }
}

extern "C" void kernel_launch(void* const* d_in, const int* in_sizes, int n_in,
                              void* d_out, int out_size, void* d_ws, size_t ws_size,
                              hipStream_t stream) {
    const float* x    = (const float*)d_in[0];  // (N, C, HW) fp32
    const float* grid = (const float*)d_in[1];  // (N, H, W, 2) fp32
    float* out = (float*)d_out;                 // (N, C, HW) fp32

    const int H = 64, W = 64;
    const int HW = H * W;
    const int N = in_sizes[1] / (HW * 2);
    const int C = in_sizes[0] / (N * HW);

    if (N == 4 && C == 128) {
        hipLaunchKernelGGL((fused_remap2_t<4, 128, 64, 64>), dim3(N * C / 2),
                           dim3(1024), 0, stream, x, grid, out);
    } else {
        const size_t shmem = (size_t)HW * sizeof(float);
        hipLaunchKernelGGL(fused_remap_generic, dim3(N * C), dim3(1024), shmem,
                           stream, x, grid, out, N, C, H, W);
    }
}